// Round 7
// baseline (19.862 us; speedup 1.0000x reference)
//
#include <hip/hip_runtime.h>

// SVR inference: out[i] = sum_j exp(-|f_i-f_j|^2/50) * alpha[j] + bias
// N=4096, D=64.  Round 7 = Round 6 with the compile fix: __exp2f (CUDA-only)
// -> exp2f (HIP: __ocml_exp2_f32 -> v_exp_f32, which is natively 2^x).
//
// Frag map (16x16x32 bf16): lane l of tile t, k-half h holds
//   row = 16*t + (l&15), k = 32*h + (l>>4)*8 .. +7  -> chunk id (t*2+h)*64+l.
// A/B frags share the lane->k map => k-permutation cancels in A.B.
// C/D: col=lane&15 (i), row=(lane>>4)*4+reg (j)   [verified m89; R4/R5 passed]
//
// exp2 domain: exp(-(si+sj-2dot)/50) = exp2(dot*K1 - si2 - sj2),
//   sq2[i] = |f_i|^2 * log2(e)/50,  K1 = 2*log2(e)/50.

#define NN 4096
#define DD 64
#define JC 32                  // j-chunks: per block 128 j = 8 tiles
#define NT (NN / 16)           // 256 row-tiles

typedef __attribute__((ext_vector_type(8))) short bf16x8;
typedef __attribute__((ext_vector_type(8))) unsigned short u16x8;
typedef __attribute__((ext_vector_type(4))) float f32x4;

#define K1 0.057707802f        // 2*log2(e)/50
#define C2 0.028853901f        // log2(e)/50

static __device__ __forceinline__ unsigned short f2bf(float f) {
    unsigned int x = __float_as_uint(f);
    x += 0x7fffu + ((x >> 16) & 1u);          // RNE
    return (unsigned short)(x >> 16);
}

// ---------- prep: retile+convert; row norms from the same registers ----------
__global__ __launch_bounds__(256) void svr_prep(const float* __restrict__ F,
                                                const float* __restrict__ bias,
                                                u16x8* __restrict__ Ft,
                                                float* __restrict__ sq2,
                                                float* __restrict__ out) {
    __shared__ float part[256];
    const int tid = threadIdx.x;
    const int g = blockIdx.x * 256 + tid;           // 0..32767
    const int l = g & 63;
    const int h = (g >> 6) & 1;
    const int t = g >> 7;
    const int row = t * 16 + (l & 15);
    const int k0  = h * 32 + (l >> 4) * 8;

    const float4* src = reinterpret_cast<const float4*>(F + (size_t)row * DD + k0);
    const float4 v0 = src[0];
    const float4 v1 = src[1];
    u16x8 u;
    u[0] = f2bf(v0.x); u[1] = f2bf(v0.y); u[2] = f2bf(v0.z); u[3] = f2bf(v0.w);
    u[4] = f2bf(v1.x); u[5] = f2bf(v1.y); u[6] = f2bf(v1.z); u[7] = f2bf(v1.w);
    Ft[g] = u;

    // partial |row|^2 from the 8 elems already loaded
    float p = v0.x * v0.x;
    p = fmaf(v0.y, v0.y, p); p = fmaf(v0.z, v0.z, p); p = fmaf(v0.w, v0.w, p);
    p = fmaf(v1.x, v1.x, p); p = fmaf(v1.y, v1.y, p); p = fmaf(v1.z, v1.z, p);
    p = fmaf(v1.w, v1.w, p);
    part[tid] = p;
    __syncthreads();
    if ((tid & 112) == 0) {    // one thread per row: tid in {0..15, 128..143}
        float s = part[tid]      + part[tid + 16] + part[tid + 32] + part[tid + 48]
                + part[tid + 64] + part[tid + 80] + part[tid + 96] + part[tid + 112];
        sq2[row] = s * C2;
    }
    if (g < NN) out[g] = bias[0];   // re-init every call (atomics accumulate)
}

// ---------- main: fused gram-tile + exp2 + alpha matvec ----------
__global__ __launch_bounds__(256) void svr_mfma(const bf16x8* __restrict__ Ft,
                                                const float* __restrict__ alpha,
                                                const float* __restrict__ sq2,
                                                float* __restrict__ out) {
    const int lane = threadIdx.x & 63;
    const int wave = threadIdx.x >> 6;
    const int it   = blockIdx.x * 4 + wave;          // i-tile 0..255
    const int iBase = it * 16;
    const int jt0  = blockIdx.y * (NT / JC);         // 8 j-tiles per block
    const int kg   = lane >> 4;
    const int c    = lane & 15;

    // B fragments: this wave's 16 i-rows, resident all loop (1KB coalesced).
    const bf16x8 b0 = Ft[it * 128 + lane];
    const bf16x8 b1 = Ft[it * 128 + 64 + lane];
    const float si2 = sq2[iBase + c];

    const float4* sqv = reinterpret_cast<const float4*>(sq2);
    const float4* alv = reinterpret_cast<const float4*>(alpha);

    f32x4 acc = {0.f, 0.f, 0.f, 0.f};

    bf16x8 a0 = Ft[jt0 * 128 + lane];
    bf16x8 a1 = Ft[jt0 * 128 + 64 + lane];
    float4 sj = sqv[jt0 * 4 + kg];
    float4 aj = alv[jt0 * 4 + kg];

#pragma unroll
    for (int k = 0; k < NT / JC; ++k) {
        bf16x8 n0, n1;
        float4 nsj, naj;
        if (k + 1 < NT / JC) {                       // prefetch next tile
            const int jn = jt0 + k + 1;
            n0 = Ft[jn * 128 + lane];
            n1 = Ft[jn * 128 + 64 + lane];
            nsj = sqv[jn * 4 + kg];
            naj = alv[jn * 4 + kg];
        }
        f32x4 d0 = {0.f, 0.f, 0.f, 0.f};
        f32x4 d1 = {0.f, 0.f, 0.f, 0.f};
        d0 = __builtin_amdgcn_mfma_f32_16x16x32_bf16(a0, b0, d0, 0, 0, 0);  // k 0..31
        d1 = __builtin_amdgcn_mfma_f32_16x16x32_bf16(a1, b1, d1, 0, 0, 0);  // k 32..63
        // d0[r]+d1[r] = dot(f_{j}, f_{i}),  j = 16*(jt0+k)+kg*4+r, i = iBase+c

        acc.x = fmaf(exp2f(fmaf(d0[0] + d1[0], K1, -(si2 + sj.x))), aj.x, acc.x);
        acc.y = fmaf(exp2f(fmaf(d0[1] + d1[1], K1, -(si2 + sj.y))), aj.y, acc.y);
        acc.z = fmaf(exp2f(fmaf(d0[2] + d1[2], K1, -(si2 + sj.z))), aj.z, acc.z);
        acc.w = fmaf(exp2f(fmaf(d0[3] + d1[3], K1, -(si2 + sj.w))), aj.w, acc.w);

        a0 = n0; a1 = n1; sj = nsj; aj = naj;
    }

    float s = (acc.x + acc.y) + (acc.z + acc.w);
    s += __shfl_xor(s, 16);
    s += __shfl_xor(s, 32);
    if (lane < 16) atomicAdd(&out[iBase + lane], s);
}

// ---------------- launch ----------------
extern "C" void kernel_launch(void* const* d_in, const int* in_sizes, int n_in,
                              void* d_out, int out_size, void* d_ws, size_t ws_size,
                              hipStream_t stream) {
    const float* F     = (const float*)d_in[0];
    const float* alpha = (const float*)d_in[1];
    const float* bias  = (const float*)d_in[2];
    float* out = (float*)d_out;

    u16x8* Ft  = (u16x8*)d_ws;                                  // 512 KB tiled bf16
    float* sq2 = (float*)((char*)d_ws + (size_t)NN * DD * 2);   // 16 KB scaled norms

    svr_prep<<<dim3(NN * DD / 8 / 256), dim3(256), 0, stream>>>(F, bias, Ft, sq2, out);
    svr_mfma<<<dim3(NT / 4, JC), dim3(256), 0, stream>>>((const bf16x8*)Ft, alpha, sq2, out);
}